// Round 11
// baseline (1192.114 us; speedup 1.0000x reference)
//
#include <hip/hip_runtime.h>
#include <hip/hip_bf16.h>
#include <math.h>

#define SEQ     512
#define BSZ     2
#define ROWS    (BSZ*SEQ)      // 1024
#define DMODEL  768
#define DINNER  1536
#define DSTATE  64
#define NHEADS  24
#define HEADDIM 64
#define CONVDIM 1664
#define DINPROJ 3224
#define DFF     3072
#define EPSF    1e-5f

__device__ __forceinline__ float b2f(const __hip_bfloat16 v){ return __bfloat162float(v); }
__device__ __forceinline__ __hip_bfloat16 f2b(float v){ return __float2bfloat16(v); }

__device__ __forceinline__ float block_sum256(float v, float* sh){
  #pragma unroll
  for (int off = 32; off > 0; off >>= 1) v += __shfl_down(v, off, 64);
  int w = threadIdx.x >> 6;
  if ((threadIdx.x & 63) == 0) sh[w] = v;
  __syncthreads();
  float t = sh[0] + sh[1] + sh[2] + sh[3];
  __syncthreads();
  return t;
}

__global__ __launch_bounds__(256) void zerof_kernel(float* out, int n){
  int i = blockIdx.x*256 + threadIdx.x;
  if (i < n) out[i] = 0.f;
}

// ---- LayerNorm over 768: fp32 in, fp32 params, bf16 out (internal) ----
__global__ __launch_bounds__(256) void ln_kernel(const float* __restrict__ in,
    const float* __restrict__ w, const float* __restrict__ b,
    __hip_bfloat16* __restrict__ out)
{
  __shared__ float sh[4];
  const int row = blockIdx.x;
  const float* xr = in + (size_t)row * DMODEL;
  float v[3]; float s = 0.f;
  #pragma unroll
  for (int i = 0; i < 3; i++){ int c = threadIdx.x + i*256; v[i] = xr[c]; s += v[i]; }
  s = block_sum256(s, sh);
  float mu = s * (1.f/DMODEL);
  float s2 = 0.f;
  #pragma unroll
  for (int i = 0; i < 3; i++){ float d = v[i]-mu; s2 += d*d; }
  s2 = block_sum256(s2, sh);
  float rs = rsqrtf(s2*(1.f/DMODEL) + EPSF);
  #pragma unroll
  for (int i = 0; i < 3; i++){
    int c = threadIdx.x + i*256;
    out[(size_t)row*DMODEL + c] = f2b((v[i]-mu)*rs*w[c] + b[c]);
  }
}

// ---- VALU GEMM: C(MxN) = A(MxK, bf16 internal) @ B(NxK, fp32 weights)^T ----
template<typename CTy>
__global__ __launch_bounds__(256) void gemm_valu(const __hip_bfloat16* __restrict__ A,
    const float* __restrict__ B, CTy* __restrict__ C, int M, int N, int K)
{
  __shared__ float As[64][33];
  __shared__ float Bs[64][33];
  const int tid = threadIdx.x;
  const int tx = tid & 15, ty = tid >> 4;
  const int n0 = blockIdx.x * 64, m0 = blockIdx.y * 64;
  float acc[4][4] = {};
  for (int k0 = 0; k0 < K; k0 += 32){
    for (int i = tid; i < 64*32; i += 256){
      int r = i >> 5, c = i & 31;
      As[r][c] = b2f(A[(size_t)(m0 + r)*K + k0 + c]);
      int nr = n0 + r; if (nr > N-1) nr = N-1;   // clamp; garbage cols never stored
      Bs[r][c] = B[(size_t)nr*K + k0 + c];
    }
    __syncthreads();
    for (int kk = 0; kk < 32; kk++){
      float av[4], bv[4];
      #pragma unroll
      for (int i = 0; i < 4; i++) av[i] = As[ty*4+i][kk];
      #pragma unroll
      for (int j = 0; j < 4; j++) bv[j] = Bs[tx*4+j][kk];
      #pragma unroll
      for (int i = 0; i < 4; i++){
        #pragma unroll
        for (int j = 0; j < 4; j++) acc[i][j] = fmaf(av[i], bv[j], acc[i][j]);
      }
    }
    __syncthreads();
  }
  #pragma unroll
  for (int i = 0; i < 4; i++){
    int rowg = m0 + ty*4 + i;
    #pragma unroll
    for (int j = 0; j < 4; j++){
      int col = n0 + tx*4 + j;
      if (col < N){
        if constexpr (sizeof(CTy) == 4) C[(size_t)rowg*N + col] = acc[i][j];
        else                            C[(size_t)rowg*N + col] = (CTy)f2b(acc[i][j]);
      }
    }
  }
}

// ---- causal depthwise conv(4) + bias + silu (both dirs) + dt/dA prep ----
// grid (SEQ, BSZ, 2). dir=1 in flipped (scan-time) coords; zx is bf16 internal.
__global__ __launch_bounds__(256) void convdt_kernel(const __hip_bfloat16* __restrict__ zx,
    const float* __restrict__ cw, const float* __restrict__ cb,
    const float* __restrict__ dt_bias, const float* __restrict__ A_log,
    __hip_bfloat16* __restrict__ xconv, float* __restrict__ dtb, float* __restrict__ dab)
{
  const int tt = blockIdx.x, b = blockIdx.y, dir = blockIdx.z;
  size_t rowoff[4]; bool ok[4];
  #pragma unroll
  for (int k = 0; k < 4; k++){
    int s = tt - 3 + k;
    ok[k] = (s >= 0);
    int ss = ok[k] ? s : 0;
    int phys = dir ? (SEQ-1-ss) : ss;
    rowoff[k] = ((size_t)(b*SEQ + phys))*DINPROJ + DINNER;
  }
  __hip_bfloat16* outr = xconv + ((size_t)((dir*BSZ + b)*SEQ + tt))*CONVDIM;
  for (int c = threadIdx.x; c < CONVDIM; c += 256){
    float acc = cb[c];
    #pragma unroll
    for (int k = 0; k < 4; k++){
      if (ok[k]) acc += cw[c*4 + k] * b2f(zx[rowoff[k] + c]);
    }
    outr[c] = f2b(acc / (1.f + expf(-acc)));   // silu
  }
  if (dir == 0 && threadIdx.x < NHEADS){
    int h = threadIdx.x;
    size_t r = (size_t)b*SEQ + tt;
    float raw = b2f(zx[r*DINPROJ + (DINNER + CONVDIM) + h]) + dt_bias[h];
    float sp  = fmaxf(raw, 0.f) + log1pf(expf(-fabsf(raw)));   // stable softplus
    dtb[r*NHEADS + h] = sp;
    dab[r*NHEADS + h] = expf(-sp * expf(A_log[h]));
  }
}

// ---- selective scan per (h, b, dir); 4 waves split 64 states; lane = p ----
#define CT 16
__global__ __launch_bounds__(256) void scan_kernel(const __hip_bfloat16* __restrict__ xconv,
    const __hip_bfloat16* __restrict__ zx, const float* __restrict__ dtb, const float* __restrict__ dab,
    const float* __restrict__ Dp, __hip_bfloat16* __restrict__ yg)
{
  const int h = blockIdx.x, b = blockIdx.y, dir = blockIdx.z;
  const int tid = threadIdx.x, lane = tid & 63, wave = tid >> 6, nb = wave * 16;
  __shared__ __align__(16) float Bc[CT][64], Cc[CT][64], Xc[CT][64];
  __shared__ __align__(16) float Yp[4][CT][64];
  __shared__ float dAc[CT], dtc[CT];
  float hreg[16];
  #pragma unroll
  for (int j = 0; j < 16; j++) hreg[j] = 0.f;
  const float Dh = Dp[h];
  const size_t dirbase = (size_t)(dir*BSZ + b) * SEQ;

  for (int c0 = 0; c0 < SEQ; c0 += CT){
    for (int i = tid; i < CT*64; i += 256){
      int ttl = i >> 6, cc = i & 63;
      const __hip_bfloat16* rowp = xconv + (dirbase + c0 + ttl)*CONVDIM;
      Bc[ttl][cc] = b2f(rowp[DINNER + cc]);
      Cc[ttl][cc] = b2f(rowp[DINNER + DSTATE + cc]);
      Xc[ttl][cc] = b2f(rowp[h*HEADDIM + cc]);
    }
    if (tid < CT){
      int phys = dir ? (SEQ-1 - (c0 + tid)) : (c0 + tid);
      size_t r = (size_t)b*SEQ + phys;
      dAc[tid] = dab[r*NHEADS + h];
      dtc[tid] = dtb[r*NHEADS + h];
    }
    __syncthreads();

    #pragma unroll 4
    for (int tt = 0; tt < CT; tt++){
      float dA = dAc[tt], dtv = dtc[tt];
      float dtx = dtv * Xc[tt][lane];
      float y0 = 0.f, y1 = 0.f, y2 = 0.f, y3 = 0.f;
      #pragma unroll
      for (int q = 0; q < 4; q++){
        int j = q*4, n = nb + j;
        float B0 = Bc[tt][n+0], B1 = Bc[tt][n+1], B2 = Bc[tt][n+2], B3 = Bc[tt][n+3];
        float C0 = Cc[tt][n+0], C1 = Cc[tt][n+1], C2 = Cc[tt][n+2], C3 = Cc[tt][n+3];
        hreg[j+0] = fmaf(dA, hreg[j+0], dtx*B0); y0 = fmaf(hreg[j+0], C0, y0);
        hreg[j+1] = fmaf(dA, hreg[j+1], dtx*B1); y1 = fmaf(hreg[j+1], C1, y1);
        hreg[j+2] = fmaf(dA, hreg[j+2], dtx*B2); y2 = fmaf(hreg[j+2], C2, y2);
        hreg[j+3] = fmaf(dA, hreg[j+3], dtx*B3); y3 = fmaf(hreg[j+3], C3, y3);
      }
      Yp[wave][tt][lane] = (y0+y1) + (y2+y3);
    }
    __syncthreads();

    for (int i = tid; i < CT*64; i += 256){
      int ttl = i >> 6, p = i & 63;
      float y = Yp[0][ttl][p] + Yp[1][ttl][p] + Yp[2][ttl][p] + Yp[3][ttl][p]
              + Dh * Xc[ttl][p];
      int phys = dir ? (SEQ-1 - (c0 + ttl)) : (c0 + ttl);
      size_t r = (size_t)b*SEQ + phys;
      float zval = b2f(zx[r*DINPROJ + h*HEADDIM + p]);
      float sil  = zval / (1.f + expf(-zval));
      yg[((size_t)dir*ROWS + r)*DINNER + h*HEADDIM + p] = f2b(y * sil);
    }
    __syncthreads();
  }
}

// ---- per-row gated RMSNorm both dirs + combine (fp32 norm_w) -> u bf16 ----
__global__ __launch_bounds__(256) void rmscomb_kernel(const __hip_bfloat16* __restrict__ yg,
    const float* __restrict__ nw, __hip_bfloat16* __restrict__ u)
{
  __shared__ float sh[4];
  const int row = blockIdx.x;
  const __hip_bfloat16* yf = yg + (size_t)row*DINNER;
  const __hip_bfloat16* yb = yg + (size_t)(ROWS + row)*DINNER;
  float vf[6], vb[6]; float sf = 0.f, sb = 0.f;
  #pragma unroll
  for (int i = 0; i < 6; i++){
    int c = threadIdx.x + i*256;
    vf[i] = b2f(yf[c]); sf += vf[i]*vf[i];
    vb[i] = b2f(yb[c]); sb += vb[i]*vb[i];
  }
  sf = block_sum256(sf, sh);
  sb = block_sum256(sb, sh);
  float rf = rsqrtf(sf*(1.f/DINNER) + EPSF);
  float rb = rsqrtf(sb*(1.f/DINNER) + EPSF);
  #pragma unroll
  for (int i = 0; i < 6; i++){
    int c = threadIdx.x + i*256;
    u[(size_t)row*DINNER + c] = f2b((vf[i]*rf + vb[i]*rb) * nw[c]);
  }
}

// ---- ln2 on fp32 mo -> bf16 mb ----
__global__ __launch_bounds__(256) void ln2_kernel(const float* __restrict__ in,
    const float* __restrict__ w, const float* __restrict__ b,
    __hip_bfloat16* __restrict__ out)
{
  __shared__ float sh[4];
  const int row = blockIdx.x;
  const float* xr = in + (size_t)row * DMODEL;
  float v[3]; float s = 0.f;
  #pragma unroll
  for (int i = 0; i < 3; i++){ int c = threadIdx.x + i*256; v[i] = xr[c]; s += v[i]; }
  s = block_sum256(s, sh);
  float mu = s * (1.f/DMODEL);
  float s2 = 0.f;
  #pragma unroll
  for (int i = 0; i < 3; i++){ float d = v[i]-mu; s2 += d*d; }
  s2 = block_sum256(s2, sh);
  float rs = rsqrtf(s2*(1.f/DMODEL) + EPSF);
  #pragma unroll
  for (int i = 0; i < 3; i++){
    int c = threadIdx.x + i*256;
    out[(size_t)row*DMODEL + c] = f2b((v[i]-mu)*rs*w[c] + b[c]);
  }
}

// ---- exact GELU with fp32 bias: bf16 g -> bf16 gb ----
__global__ __launch_bounds__(256) void gelu_kernel(const __hip_bfloat16* __restrict__ g,
    const float* __restrict__ b1, __hip_bfloat16* __restrict__ out)
{
  size_t idx = (size_t)blockIdx.x*256 + threadIdx.x;
  int c = (int)(idx % DFF);
  float v = b2f(g[idx]) + b1[c];
  out[idx] = f2b(0.5f * v * (1.f + erff(v * 0.70710678118654752f)));
}

// ---- final: fp32 fo + fp32 bias + fp32 x -> fp32 out ----
__global__ __launch_bounds__(256) void final_kernel(const float* __restrict__ f,
    const float* __restrict__ bias, const float* __restrict__ x,
    float* __restrict__ out)
{
  size_t idx = (size_t)blockIdx.x*256 + threadIdx.x;
  int c = (int)(idx % DMODEL);
  out[idx] = f[idx] + bias[c] + x[idx];
}

extern "C" void kernel_launch(void* const* d_in, const int* in_sizes, int n_in,
                              void* d_out, int out_size, void* d_ws, size_t ws_size,
                              hipStream_t stream)
{
  float* out = (float*)d_out;

  const size_t NEED = 19906560;   // proven to fit (r3 guard passed)
  if (ws_size < NEED || n_in < 17){
    zerof_kernel<<<(out_size + 255)/256, 256, 0, stream>>>(out, out_size);
    return;
  }

  const float* x       = (const float*)d_in[0];
  const float* in_proj_w = (const float*)d_in[1];
  const float* conv_w  = (const float*)d_in[2];
  const float* conv_b  = (const float*)d_in[3];
  const float* dt_bias = (const float*)d_in[4];
  const float* A_log   = (const float*)d_in[5];
  const float* D_param = (const float*)d_in[6];
  const float* norm_w  = (const float*)d_in[7];
  const float* out_proj_w = (const float*)d_in[8];
  const float* ln1_w   = (const float*)d_in[9];
  const float* ln1_b   = (const float*)d_in[10];
  const float* ln2_w   = (const float*)d_in[11];
  const float* ln2_b   = (const float*)d_in[12];
  const float* ff_w1   = (const float*)d_in[13];
  const float* ff_b1   = (const float*)d_in[14];
  const float* ff_w2   = (const float*)d_in[15];
  const float* ff_b2   = (const float*)d_in[16];

  // bf16-internal workspace, same proven 19.9 MB plan as r3:
  char* ws = (char*)d_ws;
  __hip_bfloat16* zx  = (__hip_bfloat16*)(ws + 0);         // 6,602,752
  __hip_bfloat16* xn  = (__hip_bfloat16*)(ws + 6602752);   // 1,572,864 (dead after s2)
  float*          dtb = (float*)(ws + 6602752);            //    98,304 (over xn)
  float*          dab = (float*)(ws + 6701056);            //    98,304
  __hip_bfloat16* xcv = (__hip_bfloat16*)(ws + 6799360);   // 6,815,744 -> 13,615,104
  __hip_bfloat16* yg  = (__hip_bfloat16*)(ws + 13615104);  // 6,291,456 -> 19,906,560
  __hip_bfloat16* u   = (__hip_bfloat16*)(ws + 0);         // over zx (dead after scan)
  float*          mo  = (float*)(ws + 3145728);            // over zx
  __hip_bfloat16* mb  = (__hip_bfloat16*)(ws + 0);         // over u (dead)
  __hip_bfloat16* g   = (__hip_bfloat16*)(ws + 6799360);   // over xcv (dead)
  __hip_bfloat16* gb  = (__hip_bfloat16*)(ws + 13615104);  // over yg (dead)
  float*          fo  = (float*)(ws + 0);                  // over mb (dead)

  // 1) ln1(x) -> xn
  ln_kernel<<<ROWS, 256, 0, stream>>>(x, ln1_w, ln1_b, xn);
  // 2) in_proj (shared fwd/bwd) -> zx bf16
  gemm_valu<<<dim3((DINPROJ+63)/64, ROWS/64), 256, 0, stream>>>(xn, in_proj_w, zx, ROWS, DINPROJ, DMODEL);
  // 3) conv + silu + dt/dA
  convdt_kernel<<<dim3(SEQ, BSZ, 2), 256, 0, stream>>>(zx, conv_w, conv_b, dt_bias, A_log, xcv, dtb, dab);
  // 4) scan + D*x + silu(z) gate -> yg
  scan_kernel<<<dim3(NHEADS, BSZ, 2), 256, 0, stream>>>(xcv, zx, dtb, dab, D_param, yg);
  // 5) per-dir RMS + combine -> u
  rmscomb_kernel<<<ROWS, 256, 0, stream>>>(yg, norm_w, u);
  // 6) out_proj -> mo fp32
  gemm_valu<<<dim3(DMODEL/64, ROWS/64), 256, 0, stream>>>(u, out_proj_w, mo, ROWS, DMODEL, DINNER);
  // 7) ln2 -> mb
  ln2_kernel<<<ROWS, 256, 0, stream>>>(mo, ln2_w, ln2_b, mb);
  // 8) ff1 -> g
  gemm_valu<<<dim3(DFF/64, ROWS/64), 256, 0, stream>>>(mb, ff_w1, g, ROWS, DFF, DMODEL);
  // 9) gelu -> gb
  gelu_kernel<<<(ROWS*DFF)/256, 256, 0, stream>>>(g, ff_b1, gb);
  // 10) ff2 -> fo fp32
  gemm_valu<<<dim3(DMODEL/64, ROWS/64), 256, 0, stream>>>(gb, ff_w2, fo, ROWS, DMODEL, DFF);
  // 11) + b2 + residual -> out fp32
  final_kernel<<<(ROWS*DMODEL)/256, 256, 0, stream>>>(fo, ff_b2, x, out);
}